// Round 3
// baseline (61.575 us; speedup 1.0000x reference)
//
#include <hip/hip_runtime.h>

// Problem constants (B=8, U=512, F=64, R=256)
#define BU   4096      // B*U rows of x
#define F_   64
#define R_   256
#define ROWS_PER_BLOCK 16

// fp64 -> fp32 with flush-to-zero for denormal results, matching the
// XLA/GPU fp32 reference semantics (f32 denormals flushed). d >= 0.
// Verified round 2: absmax 0.0 (bit-exact vs np reference).
__device__ __forceinline__ float d2f_ftz(double d) {
    return (d >= 0x1.0p-126) ? (float)d : 0.0f;
}

__global__ __launch_bounds__(256) void rules_outer_kernel(
        const float* __restrict__ x,        // [BU, F]
        const float* __restrict__ rules,    // [R, F]
        float* __restrict__ out)            // [BU, R]
{
    __shared__ double sPr[R_];
    __shared__ double sPx[ROWS_PER_BLOCK];

    const int t   = threadIdx.x;            // 0..255
    const int bu0 = blockIdx.x * ROWS_PER_BLOCK;

    // ---- issue the x load FIRST so its latency overlaps the Pr chain ----
    const int xr = t >> 4;                  // row 0..15
    const int xc = t & 15;                  // float4 index 0..15
    const float4 xv = *(const float4*)(x + (size_t)(bu0 + xr) * F_ + xc * 4);

    // ---- Pr[t] = prod_f rules[t][f] in fp64, 4 independent chains ----
    {
        const float4* rp = (const float4*)(rules + t * F_);
        double a0 = 1.0, a1 = 1.0, a2 = 1.0, a3 = 1.0;
        #pragma unroll
        for (int i = 0; i < 4; ++i) {
            float4 v0 = rp[i + 0], v1 = rp[i + 4], v2 = rp[i + 8], v3 = rp[i + 12];
            a0 *= (double)v0.x * (double)v0.y; a0 *= (double)v0.z * (double)v0.w;
            a1 *= (double)v1.x * (double)v1.y; a1 *= (double)v1.z * (double)v1.w;
            a2 *= (double)v2.x * (double)v2.y; a2 *= (double)v2.z * (double)v2.w;
            a3 *= (double)v3.x * (double)v3.y; a3 *= (double)v3.z * (double)v3.w;
        }
        sPr[t] = (a0 * a1) * (a2 * a3);
    }

    // ---- Px: 16 threads per row, product-reduce via shfl_xor (all 256 busy) ----
    {
        double q = ((double)xv.x * (double)xv.y) * ((double)xv.z * (double)xv.w);
        #pragma unroll
        for (int m = 1; m <= 8; m <<= 1)
            q *= __shfl_xor(q, m, 64);      // partners stay inside the 16-lane group
        if (xc == 0) sPx[xr] = q;
    }
    __syncthreads();

    // ---- outer product tile: 16 rows x 256 cols, float4 stores ----
    const int c    = t & 63;                // column group (4 cols each)
    const int rowl = t >> 6;                // 0..3
    const int r0   = c * 4;

    const double pr0 = sPr[r0 + 0];
    const double pr1 = sPr[r0 + 1];
    const double pr2 = sPr[r0 + 2];
    const double pr3 = sPr[r0 + 3];

    #pragma unroll
    for (int pass = 0; pass < 4; ++pass) {
        const int row = pass * 4 + rowl;
        const double px = sPx[row];
        float4 o;
        o.x = d2f_ftz(px * pr0);
        o.y = d2f_ftz(px * pr1);
        o.z = d2f_ftz(px * pr2);
        o.w = d2f_ftz(px * pr3);
        *(float4*)(out + (size_t)(bu0 + row) * R_ + r0) = o;
    }
}

extern "C" void kernel_launch(void* const* d_in, const int* in_sizes, int n_in,
                              void* d_out, int out_size, void* d_ws, size_t ws_size,
                              hipStream_t stream) {
    const float* x     = (const float*)d_in[0];   // [8,512,64]
    const float* rules = (const float*)d_in[1];   // [256,64]
    // d_in[2] = epoch (unused)
    float* out = (float*)d_out;                   // [8,512,256]

    rules_outer_kernel<<<BU / ROWS_PER_BLOCK, 256, 0, stream>>>(x, rules, out);
}